// Round 8
// baseline (513.062 us; speedup 1.0000x reference)
//
#include <hip/hip_runtime.h>

typedef __bf16 bf16;
typedef __bf16 bf16x4 __attribute__((ext_vector_type(4)));
typedef __bf16 bf16x8 __attribute__((ext_vector_type(8)));
typedef float floatx4 __attribute__((ext_vector_type(4)));
typedef float floatx16 __attribute__((ext_vector_type(16)));

#define SCALE_QK 0.044194173824159216f
#define INV_SQRT2F 0.7071067811865476f
#define TEN  8388608L     // elems per activation tensor (4*512*4096)
#define SBAT 2097152L     // elems per batch (4096*512)

// address-space helper types for global_load_lds
typedef const __attribute__((address_space(1))) void GV;
typedef __attribute__((address_space(3))) void SV;

// ---------------------------------------------------------------------------
// Dtype detector (verified: inputs are f32 -> flag=1; bf16 -> flag=0).
// ---------------------------------------------------------------------------
__global__ __launch_bounds__(256) void detect_k(
    const unsigned* __restrict__ q, int* __restrict__ flag)
{
    __shared__ int cnt;
    if (threadIdx.x == 0) cnt = 0;
    __syncthreads();
    int c = 0;
    for (int i = threadIdx.x; i < 4096; i += 256) {
        unsigned e = (q[i] >> 7) & 0xFFu;
        c += (e >= 100u && e <= 140u) ? 1 : 0;
    }
    atomicAdd(&cnt, c);
    __syncthreads();
    if (threadIdx.x == 0) *flag = (cnt < 3000) ? 1 : 0;
}

__global__ __launch_bounds__(256) void convw_k(
    const void* w0, const void* w1, const void* w2, const void* w3,
    bf16* __restrict__ dst, const int* __restrict__ flag)
{
    const void* srcs[4] = {w0, w1, w2, w3};
    const void* s = srcs[blockIdx.y];
    bf16* d = dst + (size_t)blockIdx.y * 262144;
    const int i = (blockIdx.x * 256 + threadIdx.x) * 8;
    bf16x8 v;
    if (*flag) {
        const float* f = (const float*)s;
        #pragma unroll
        for (int r = 0; r < 8; ++r) v[r] = (bf16)f[i + r];
    } else {
        v = *(const bf16x8*)((const bf16*)s + i);
    }
    *(bf16x8*)(d + i) = v;
}

__global__ __launch_bounds__(256) void convp_k(
    const void* p0, const void* p1, const void* p2,
    const void* p3, const void* p4, const void* p5,
    float* __restrict__ dst, const int* __restrict__ flag)
{
    const void* srcs[6] = {p0, p1, p2, p3, p4, p5};
    const int f = *flag;
    for (int i = threadIdx.x; i < 3072; i += 256) {
        const void* s = srcs[i >> 9];
        const int off = i & 511;
        dst[i] = f ? ((const float*)s)[off] : (float)((const bf16*)s)[off];
    }
}

// ---------------------------------------------------------------------------
// GroupNorm: q [4][512][4096] -> XN [4][4096][512] bf16.
// ---------------------------------------------------------------------------
__global__ __launch_bounds__(256) void groupnorm_k(
    const void* __restrict__ qraw, const float* __restrict__ gamma,
    const float* __restrict__ beta, bf16* __restrict__ XN,
    const int* __restrict__ flag)
{
    const int tid = threadIdx.x;
    const int b = blockIdx.x >> 5, g = blockIdx.x & 31;
    const int f32 = *flag;
    const size_t base = ((size_t)b * 512 + (size_t)g * 16) * 4096;
    const float* sf = (const float*)qraw + base;
    const bf16*  sb = (const bf16*)qraw + base;

    float sum = 0.f, sq = 0.f;
    if (f32) {
        const floatx4* v4 = (const floatx4*)sf;
        for (int idx = tid; idx < 16384; idx += 256) {
            floatx4 v = v4[idx];
            #pragma unroll
            for (int r = 0; r < 4; ++r) { float f = v[r]; sum += f; sq += f * f; }
        }
    } else {
        const bf16x8* v8 = (const bf16x8*)sb;
        for (int idx = tid; idx < 8192; idx += 256) {
            bf16x8 v = v8[idx];
            #pragma unroll
            for (int r = 0; r < 8; ++r) { float f = (float)v[r]; sum += f; sq += f * f; }
        }
    }
    #pragma unroll
    for (int off = 32; off; off >>= 1) {
        sum += __shfl_down(sum, off);
        sq  += __shfl_down(sq, off);
    }
    __shared__ float sS[4], sQ[4];
    __shared__ float s_mean, s_rstd;
    const int wave = tid >> 6, lane = tid & 63;
    if (lane == 0) { sS[wave] = sum; sQ[wave] = sq; }
    __syncthreads();
    if (tid == 0) {
        float ts = sS[0] + sS[1] + sS[2] + sS[3];
        float tq = sQ[0] + sQ[1] + sQ[2] + sQ[3];
        float mean = ts * (1.0f / 65536.0f);
        float var  = tq * (1.0f / 65536.0f) - mean * mean;
        s_mean = mean;
        s_rstd = rsqrtf(fmaxf(var, 0.f) + 1e-6f);
    }
    __syncthreads();
    const float mean = s_mean, rstd = s_rstd;

    float ga[16], be[16];
    #pragma unroll
    for (int c = 0; c < 16; ++c) {
        ga[c] = gamma[g * 16 + c] * rstd;
        be[c] = beta[g * 16 + c] - mean * ga[c];
    }
    bf16* dst = XN + (size_t)b * SBAT + (size_t)g * 16;
    for (int p0 = 0; p0 < 4096; p0 += 256) {
        const int p = p0 + tid;
        bf16x8 o0, o1;
        #pragma unroll
        for (int c = 0; c < 8; ++c) {
            float v = f32 ? sf[(size_t)c * 4096 + p] : (float)sb[(size_t)c * 4096 + p];
            o0[c] = (bf16)(v * ga[c] + be[c]);
        }
        #pragma unroll
        for (int c = 0; c < 8; ++c) {
            float v = f32 ? sf[(size_t)(c + 8) * 4096 + p] : (float)sb[(size_t)(c + 8) * 4096 + p];
            o1[c] = (bf16)(v * ga[c + 8] + be[c + 8]);
        }
        bf16* dp = dst + (size_t)p * 512;
        *(bf16x8*)dp = o0;
        *(bf16x8*)(dp + 8) = o1;
    }
}

// ---------------------------------------------------------------------------
// Fused attention v4: producer-consumer waves + DEEP prefetch (T3+T4).
// Block = (batch, 64 q-rows), 8 waves, 1 blk/CU, 160KB LDS (exact).
// 8 subs/chunk; slot = K[128key][64kd] 16KB + V[512c][16i] 16KB; FOUR
// buffers each (8 % 4 == 0 -> buffer index = s&3, compile-time). Stage for
// sub g issued at g-3; every sub head does counted vmcnt(8) (keep newest 2
// subs' 8 loads) + raw barrier -- NO vmcnt(0) drain in the loop (the R5-R7
// per-sub drain was the exposed-latency serializer).
//   Waves 0-3 (QK): 2 j-halves x 2 key-halves; Q[32j x 512kd] in regs.
//     Per sub: 2 ksl x {4 K-frag reads (conflict-free XOR), 8 MFMA}.
//     Sub 7 tail: exp + packed P(c) write to buf c&1 + rowsum partial.
//   Waves 4-7 (PV): 128 c-cols each; consume P(c-1)/V(c-1); per sub
//     (one 16-i k-step): 2 pa + 4 vb reads, 8 MFMA (32x32x16).
// LDS: K @0 4x16KB [row128B, XOR8 chunk^(row&7)]; V @65536 4x16KB
//      [row32B, XOR2 chunk^((row>>2)&1)]; P @131072 2x16KB [row256B, XOR16].
// ---------------------------------------------------------------------------
__global__ __launch_bounds__(512, 1) void fused_attn(
    const bf16* __restrict__ QKt,   // [b][4096][1024]: Q cols 0-511, K cols 512-1023
    const bf16* __restrict__ V,     // [b][512][4096]
    bf16* __restrict__ AOt)         // [b][4096][512]
{
    __shared__ __align__(16) char smc[163840];

    const int tid = threadIdx.x;
    const int w = tid >> 6, lane = tid & 63;
    const int fr = lane & 15, quad = lane >> 4;
    const int l5 = lane >> 5, l31 = lane & 31;

    // XCD->batch mapping: xcd = id%8; XCD pair owns one batch's K/V (L2-local)
    const int ll = blockIdx.x;
    const int xcd = ll & 7, rr = ll >> 3;
    const int b = xcd >> 1;
    const int j0 = ((xcd & 1) * 32 + rr) * 64;

    const bf16* Qb = QKt + (size_t)b * 4194304;
    const bf16* Kb = Qb + 512;
    const bf16* Vb = V + (size_t)b * SBAT;

    // ---- staging constants (dest lane-linear; source col pre-XOR'd) ----
    // K slot [128 key][64 kd]: instr rho in {0,1}: row = rho*64 + t/8,
    // chunk16B = t&7, logical = chunk ^ (row&7).
    const int krow0 = tid >> 3;
    const int klog  = ((tid & 7) ^ ((tid >> 3) & 7)) << 3;   // elems
    // V slot [512 c][16 i]: rho in {0,1}: row = rho*256 + t/2, chunk = t&1,
    // logical = chunk ^ ((row>>2)&1).
    const int vrow0 = tid >> 1;
    const int vlog  = ((tid & 1) ^ ((tid >> 3) & 1)) << 3;   // elems

    auto stage_for = [&](int kcc, int ks, int vcc, int vs, int buf) {
        {   // K slot (2 loads)
            char* d = smc + buf * 16384 + tid * 16;
            const bf16* s0 = Kb + (size_t)(kcc * 128 + krow0) * 1024 + ks * 64 + klog;
            __builtin_amdgcn_global_load_lds((GV*)s0, (SV*)d, 16, 0, 0);
            __builtin_amdgcn_global_load_lds((GV*)(s0 + (size_t)64 * 1024),
                                             (SV*)(d + 8192), 16, 0, 0);
        }
        {   // V slot (2 loads)
            char* d = smc + 65536 + buf * 16384 + tid * 16;
            const bf16* s0 = Vb + (size_t)vrow0 * 4096 + vcc * 128 + vs * 16 + vlog;
            __builtin_amdgcn_global_load_lds((GV*)s0, (SV*)d, 16, 0, 0);
            __builtin_amdgcn_global_load_lds((GV*)(s0 + (size_t)256 * 4096),
                                             (SV*)(d + 8192), 16, 0, 0);
        }
    };

    if (w < 4) {
        // =================== QK producer path (waves 0-3) ===================
        const int jb = w >> 1;                 // j-half: 32 rows
        const int kw = w & 1;                  // key-half: 64 keys
        bf16x8 qf[2][16];                      // 32 j x 512 kd (128 VGPR)
        #pragma unroll
        for (int jj = 0; jj < 2; ++jj) {
            const bf16* qsrc = Qb +
                (size_t)(j0 + jb * 32 + jj * 16 + fr) * 1024 + quad * 8;
            #pragma unroll
            for (int s = 0; s < 16; ++s)
                qf[jj][s] = *(const bf16x8*)(qsrc + s * 32);
        }
        const int pxor = fr << 4;
        const int prow0 = (jb * 32 + fr) * 256;
        const int pcol0 = kw * 128;            // bytes
        float l_acc0 = 0.f, l_acc1 = 0.f;

        stage_for(0, 0, 0, 0, 0);
        stage_for(0, 1, 0, 1, 1);
        stage_for(0, 2, 0, 2, 2);

        for (int cc = 0; cc <= 32; ++cc) {
            floatx4 acc_s[4][2] = {};
            #pragma unroll
            for (int s = 0; s < 8; ++s) {
                asm volatile("s_waitcnt vmcnt(8)" ::: "memory");
                __builtin_amdgcn_s_barrier();
                {   // stage content for sub g+3
                    const int cy = (s + 3) >> 3, ts = (s + 3) & 7, bu = (s + 3) & 3;
                    const int kcc = (cc + cy > 31) ? 31 : cc + cy;
                    int vcc = cc + cy - 1;
                    vcc = (vcc < 0) ? 0 : ((vcc > 31) ? 31 : vcc);
                    stage_for(kcc, ts, vcc, ts, bu);
                }
                if (cc < 32) {
                    const char* kbuf = smc + (s & 3) * 16384;
                    __builtin_amdgcn_s_setprio(1);
                    #pragma unroll
                    for (int ksl = 0; ksl < 2; ++ksl) {
                        bf16x8 kfr[4];
                        #pragma unroll
                        for (int kf = 0; kf < 4; ++kf)
                            kfr[kf] = *(const bf16x8*)(kbuf +
                                (kw * 64 + kf * 16 + fr) * 128 +
                                (((ksl * 4 + quad) ^ (fr & 7)) << 4));
                        #pragma unroll
                        for (int kf = 0; kf < 4; ++kf) {
                            acc_s[kf][0] = __builtin_amdgcn_mfma_f32_16x16x32_bf16(
                                kfr[kf], qf[0][s * 2 + ksl], acc_s[kf][0], 0, 0, 0);
                            acc_s[kf][1] = __builtin_amdgcn_mfma_f32_16x16x32_bf16(
                                kfr[kf], qf[1][s * 2 + ksl], acc_s[kf][1], 0, 0, 0);
                        }
                    }
                    __builtin_amdgcn_s_setprio(0);
                    if (s == 7) {
                        // exp + packed P(cc) write to buf cc&1 + rowsum
                        char* pb = smc + 131072 + (cc & 1) * 16384;
                        float rs0 = 0.f, rs1 = 0.f;
                        #pragma unroll
                        for (int kf = 0; kf < 4; ++kf) {
                            const int cb = (pcol0 + kf * 32 + quad * 8) ^ pxor;
                            bf16x4 pk0, pk1;
                            #pragma unroll
                            for (int r = 0; r < 4; ++r) {
                                float e0 = __expf(fminf(acc_s[kf][0][r] * SCALE_QK, 30.f));
                                float e1 = __expf(fminf(acc_s[kf][1][r] * SCALE_QK, 30.f));
                                rs0 += e0; rs1 += e1;
                                pk0[r] = (bf16)e0; pk1[r] = (bf16)e1;
                            }
                            *(bf16x4*)(pb + prow0 + cb) = pk0;
                            *(bf16x4*)(pb + prow0 + 4096 + cb) = pk1;
                        }
                        rs0 += __shfl_xor(rs0, 16);
                        rs0 += __shfl_xor(rs0, 32);
                        rs1 += __shfl_xor(rs1, 16);
                        rs1 += __shfl_xor(rs1, 32);
                        l_acc0 += rs0; l_acc1 += rs1;
                        asm volatile("s_waitcnt lgkmcnt(0)" ::: "memory");
                    }
                }
            }
        }
        __syncthreads();                       // drains vmcnt too (LDS reuse safe)
        float* lp = (float*)smc;               // [2][64] (K bufs dead)
        if (lane < 16) {
            lp[kw * 64 + jb * 32 + lane] = l_acc0;
            lp[kw * 64 + jb * 32 + 16 + lane] = l_acc1;
        }
        __syncthreads();
    } else {
        // =================== PV consumer path (waves 4-7) ===================
        const int pw = w - 4;                  // 128 c-cols per wave
        floatx16 acc_o[2][4] = {};

        stage_for(0, 0, 0, 0, 0);
        stage_for(0, 1, 0, 1, 1);
        stage_for(0, 2, 0, 2, 2);

        for (int cc = 0; cc <= 32; ++cc) {
            #pragma unroll
            for (int s = 0; s < 8; ++s) {
                asm volatile("s_waitcnt vmcnt(8)" ::: "memory");
                __builtin_amdgcn_s_barrier();
                {
                    const int cy = (s + 3) >> 3, ts = (s + 3) & 7, bu = (s + 3) & 3;
                    const int kcc = (cc + cy > 31) ? 31 : cc + cy;
                    int vcc = cc + cy - 1;
                    vcc = (vcc < 0) ? 0 : ((vcc > 31) ? 31 : vcc);
                    stage_for(kcc, ts, vcc, ts, bu);
                }
                if (cc >= 1) {
                    const char* vb = smc + 65536 + (s & 3) * 16384;
                    const char* pb = smc + 131072 + ((cc - 1) & 1) * 16384;
                    __builtin_amdgcn_s_setprio(1);
                    bf16x8 pa[2];
                    #pragma unroll
                    for (int jf = 0; jf < 2; ++jf)
                        pa[jf] = *(const bf16x8*)(pb + (jf * 32 + l31) * 256 +
                            (((s * 2 + l5) ^ (l31 & 15)) << 4));
                    #pragma unroll
                    for (int nf = 0; nf < 4; ++nf) {
                        const int vc = pw * 128 + nf * 32 + l31;
                        bf16x8 vb8 = *(const bf16x8*)(vb + vc * 32 +
                            ((l5 ^ ((vc >> 2) & 1)) << 4));
                        acc_o[0][nf] = __builtin_amdgcn_mfma_f32_32x32x16_bf16(
                            pa[0], vb8, acc_o[0][nf], 0, 0, 0);
                        acc_o[1][nf] = __builtin_amdgcn_mfma_f32_32x32x16_bf16(
                            pa[1], vb8, acc_o[1][nf], 0, 0, 0);
                    }
                    __builtin_amdgcn_s_setprio(0);
                }
            }
        }
        __syncthreads();                       // QK waves write lp here
        __syncthreads();
        const float* lp = (const float*)smc;

        bf16* out = AOt + (size_t)b * SBAT + (size_t)j0 * 512;
        #pragma unroll
        for (int jf = 0; jf < 2; ++jf) {
            #pragma unroll
            for (int reg = 0; reg < 16; ++reg) {
                const int j = jf * 32 + (reg & 3) + 8 * (reg >> 2) + 4 * l5;
                const float rl = 1.0f / fmaxf(lp[j] + lp[64 + j], 1e-30f);
                #pragma unroll
                for (int nf = 0; nf < 4; ++nf) {
                    const int d = pw * 128 + nf * 32 + l31;
                    out[(size_t)j * 512 + d] = (bf16)(acc_o[jf][nf][reg] * rl);
                }
            }
        }
    }
}

// ---------------------------------------------------------------------------
// 128x128x32 2-phase GEMM (projections + output).
// Epilogues: 0 bias[n] (C=[p][o]) ; 1 bias[m] (C=[o][p]) ; 4 out+residual.
// ---------------------------------------------------------------------------
template <int EPI>
__global__ __launch_bounds__(256, 4) void gemm_xyt(
    const bf16* __restrict__ Xb, const bf16* __restrict__ Yb,
    void* __restrict__ Cv, int N, int K, int lda, int ldb,
    long sX, long sY, long sC,
    const float* __restrict__ bias,
    const void* __restrict__ res, long sR,
    const int* __restrict__ flag)
{
    __shared__ __align__(16) bf16 smem[17408];

    const int tid  = threadIdx.x;
    const int wave = tid >> 6;
    const int lane = tid & 63;
    const int z = blockIdx.z;

    int bx = blockIdx.x, by = blockIdx.y;
    {
        const int gx = gridDim.x, gy = gridDim.y;
        const int o = by * gx + bx;
        const int xcd = o & 7, idx = o >> 3;
        if (gx == 8) {
            bx = xcd;
            by = idx;
        } else if (gx == 32 && gy == 4) {
            bx = (xcd & 1) * 16 + (idx & 15);
            by = xcd >> 1;
        }
    }

    const bf16* X = Xb + (long)z * sX;
    const bf16* Y = Yb + (long)z * sY;
    bf16*  Cb = (bf16*)Cv  + (long)z * sC;
    float* Cf = (float*)Cv + (long)z * sC;
    const int f32o = (EPI == 4) ? *flag : 0;

    const int m0 = by * 128, n0 = bx * 128;
    const int wm = (wave >> 1) * 64, wn = (wave & 1) * 64;
    const int fr = lane & 15, quad = lane >> 4;

    const int srow = tid >> 2;
    const int scol = (tid & 3) * 8;
    const bf16* pX = X + (size_t)(m0 + srow) * lda + scol;
    const bf16* pY = Y + (size_t)(n0 + srow) * ldb + scol;
    const size_t oX = (size_t)64 * lda, oY = (size_t)64 * ldb;
    char* const sb0 = (char*)smem;
    const int ldst = tid * 16;

    auto stage = [&](int k, int pb) {
        char* d = sb0 + pb * 16384;
        const bf16* x = pX + k * 32;
        const bf16* y = pY + k * 32;
        __builtin_amdgcn_global_load_lds((GV*)x,        (SV*)(d + ldst),         16, 0, 0);
        __builtin_amdgcn_global_load_lds((GV*)(x + oX), (SV*)(d + 4096 + ldst),  16, 0, 0);
        __builtin_amdgcn_global_load_lds((GV*)y,        (SV*)(d + 8192 + ldst),  16, 0, 0);
        __builtin_amdgcn_global_load_lds((GV*)(y + oY), (SV*)(d + 12288 + ldst), 16, 0, 0);
    };

    floatx4 acc[4][4] = {};
    const int NK = K >> 5;

    stage(0, 0);
    __syncthreads();

    for (int k = 0; k < NK; ++k) {
        const int p = k & 1;
        if (k + 1 < NK) stage(k + 1, 1 - p);
        const bf16* bA = smem + p * 8192;
        const bf16* bB = bA + 4096;
        bf16x8 af[4], bfr[4];
        #pragma unroll
        for (int i = 0; i < 4; ++i) {
            af[i]  = *(const bf16x8*)&bA[(wm + i * 16 + fr) * 32 + quad * 8];
            bfr[i] = *(const bf16x8*)&bB[(wn + i * 16 + fr) * 32 + quad * 8];
        }
        #pragma unroll
        for (int i = 0; i < 4; ++i)
            #pragma unroll
            for (int j = 0; j < 4; ++j)
                acc[i][j] = __builtin_amdgcn_mfma_f32_16x16x32_bf16(
                    af[i], bfr[j], acc[i][j], 0, 0, 0);
        __syncthreads();
    }

    #pragma unroll
    for (int i = 0; i < 4; ++i) {
        const int mg = m0 + wm + i * 16 + quad * 4;
        float bmr[4];
        if (EPI == 1 || EPI == 4) {
            #pragma unroll
            for (int r = 0; r < 4; ++r) bmr[r] = bias[mg + r];
        }
        #pragma unroll
        for (int j = 0; j < 4; ++j) {
            const int ng = n0 + wn + j * 16 + fr;
            #pragma unroll
            for (int r = 0; r < 4; ++r) {
                float v = acc[i][j][r];
                if (EPI == 0) v += bias[ng];
                if (EPI == 1) v += bmr[r];
                if (EPI == 4) v += bmr[r];
                acc[i][j][r] = v;
            }
        }
    }

    if (EPI != 4) {
        bf16* ct = smem;                       // [128][132] bf16
        #pragma unroll
        for (int i = 0; i < 4; ++i)
            #pragma unroll
            for (int j = 0; j < 4; ++j)
                #pragma unroll
                for (int r = 0; r < 4; ++r)
                    ct[(wm + i * 16 + quad * 4 + r) * 132 + wn + j * 16 + fr] =
                        (bf16)acc[i][j][r];
        __syncthreads();
        #pragma unroll
        for (int w = 0; w < 8; ++w) {
            const int idx = w * 2048 + tid * 8;
            const int row = idx >> 7, col = idx & 127;
            bf16x8 v = *(const bf16x8*)&ct[row * 132 + col];
            *(bf16x8*)&Cb[(size_t)(m0 + row) * N + n0 + col] = v;
        }
    } else if (f32o) {
        float* ct = (float*)smem;              // [64][132] f32, two halves
        const float* rres = (const float*)res + (size_t)z * sR;
        #pragma unroll
        for (int h = 0; h < 2; ++h) {
            if ((wave >> 1) == h) {
                #pragma unroll
                for (int i = 0; i < 4; ++i)
                    #pragma unroll
                    for (int j = 0; j < 4; ++j)
                        #pragma unroll
                        for (int r = 0; r < 4; ++r)
                            ct[(i * 16 + quad * 4 + r) * 132 + wn + j * 16 + fr] =
                                acc[i][j][r];
            }
            __syncthreads();
            #pragma unroll
            for (int w = 0; w < 8; ++w) {
                const int idx = (w * 256 + tid) * 4;
                const int row = idx >> 7, col = idx & 127;
                const size_t o = (size_t)(m0 + h * 64 + row) * N + n0 + col;
                floatx4 v = *(const floatx4*)&ct[row * 132 + col];
                floatx4 rv = *(const floatx4*)&rres[o];
                #pragma unroll
                for (int e = 0; e < 4; ++e) v[e] = (v[e] + rv[e]) * INV_SQRT2F;
                *(floatx4*)&Cf[o] = v;
            }
            __syncthreads();
        }
    } else {
        const bf16* resb = (const bf16*)res + (size_t)z * sR;
        #pragma unroll
        for (int i = 0; i < 4; ++i) {
            const int mg = m0 + wm + i * 16 + quad * 4;
            #pragma unroll
            for (int j = 0; j < 4; ++j) {
                const int ng = n0 + wn + j * 16 + fr;
                #pragma unroll
                for (int r = 0; r < 4; ++r) {
                    const size_t o = (size_t)(mg + r) * N + ng;
                    Cb[o] = (bf16)((acc[i][j][r] + (float)resb[o]) * INV_SQRT2F);
                }
            }
        }
    }
}

// ---------------------------------------------------------------------------
extern "C" void kernel_launch(void* const* d_in, const int* in_sizes, int n_in,
                              void* d_out, int out_size, void* d_ws, size_t ws_size,
                              hipStream_t stream)
{
    const void* q     = d_in[0];
    const void* gamma = d_in[1];
    const void* beta  = d_in[2];
    const void* wq    = d_in[3];
    const void* bq    = d_in[4];
    const void* wk    = d_in[5];
    const void* bk    = d_in[6];
    const void* wv    = d_in[7];
    const void* bv    = d_in[8];
    const void* wo    = d_in[9];
    const void* bo    = d_in[10];

    char* w = (char*)d_ws;
    int*   flag = (int*)w;   w += 16;
    float* Pf   = (float*)w; w += 6 * 512 * 4;      // gamma,beta,bq,bk,bv,bo
    bf16*  Wc   = (bf16*)w;  w += 4 * 262144 * 2;   // wq,wk,wv,wo bf16
    bf16*  XN   = (bf16*)w;  w += TEN * 2;          // reused as AOt
    bf16*  QKt  = (bf16*)w;  w += (size_t)4 * 4096 * 1024 * 2;
    bf16*  V    = (bf16*)w;  w += TEN * 2;
    bf16*  AOt  = XN;

    detect_k<<<dim3(1), 256, 0, stream>>>((const unsigned*)q, flag);
    convw_k<<<dim3(128, 4), 256, 0, stream>>>(wq, wk, wv, wo, Wc, flag);
    convp_k<<<dim3(1), 256, 0, stream>>>(gamma, beta, bq, bk, bv, bo, Pf, flag);

    groupnorm_k<<<dim3(128), 256, 0, stream>>>(q, Pf, Pf + 512, XN, flag);

    // QKt[p][0:512]=XN.Wq^T+bq, [512:1024]=XN.Wk^T+bk  (merged, N=1024, K=512)
    gemm_xyt<0><<<dim3(8, 32, 4), 256, 0, stream>>>(XN, Wc, QKt,
        1024, 512, 512, 512, SBAT, 0, (long)4096 * 1024, Pf + 1024,
        nullptr, 0, flag);
    // V[o][p] = Wv . XN^T + bv.  N=4096, K=512
    gemm_xyt<1><<<dim3(32, 4, 4), 256, 0, stream>>>(Wc + 2 * 262144, XN, V,
        4096, 512, 512, 512, 0, SBAT, SBAT, Pf + 2048,
        nullptr, 0, flag);

    // Fused scores->exp->PV->(1/l): AOt[b][j][c]  (AOt aliases XN)
    fused_attn<<<dim3(256), 512, 0, stream>>>(QKt, V, AOt);

    // out[o][p] = (Wo . AOt^T + bo + q) * inv_sqrt2.  N=4096, K=512
    gemm_xyt<4><<<dim3(32, 4, 4), 256, 0, stream>>>(Wc + 3 * 262144, AOt, d_out,
        4096, 512, 512, 512, 0, SBAT, SBAT, Pf + 2560,
        q, SBAT, flag);
}

// Round 9
// 432.903 us; speedup vs baseline: 1.1852x; 1.1852x over previous
//
#include <hip/hip_runtime.h>

typedef __bf16 bf16;
typedef __bf16 bf16x4 __attribute__((ext_vector_type(4)));
typedef __bf16 bf16x8 __attribute__((ext_vector_type(8)));
typedef float floatx4 __attribute__((ext_vector_type(4)));
typedef float floatx16 __attribute__((ext_vector_type(16)));

#define SCALE_QK 0.044194173824159216f
#define INV_SQRT2F 0.7071067811865476f
#define TEN  8388608L     // elems per activation tensor (4*512*4096)
#define SBAT 2097152L     // elems per batch (4096*512)

// address-space helper types for global_load_lds
typedef const __attribute__((address_space(1))) void GV;
typedef __attribute__((address_space(3))) void SV;

// ---------------------------------------------------------------------------
// prep_k: merged detect + weight-convert + param-convert (one launch).
// Every block computes the dtype flag LOCALLY from q's first 4096 words
// (no cross-kernel dependency). Blocks 0..511: convw (wy = blk>>7,
// bx = blk&127). Block 512: convp + publish global flag.
// ---------------------------------------------------------------------------
__global__ __launch_bounds__(256) void prep_k(
    const unsigned* __restrict__ q,
    const void* w0, const void* w1, const void* w2, const void* w3,
    const void* p0, const void* p1, const void* p2,
    const void* p3, const void* p4, const void* p5,
    bf16* __restrict__ Wc, float* __restrict__ Pf, int* __restrict__ flagp)
{
    __shared__ int cnt;
    if (threadIdx.x == 0) cnt = 0;
    __syncthreads();
    int c = 0;
    for (int i = threadIdx.x; i < 4096; i += 256) {
        unsigned e = (q[i] >> 7) & 0xFFu;
        c += (e >= 100u && e <= 140u) ? 1 : 0;
    }
    atomicAdd(&cnt, c);
    __syncthreads();
    const int flag = (cnt < 3000) ? 1 : 0;

    const int blk = blockIdx.x;
    if (blk < 512) {
        const void* srcs[4] = {w0, w1, w2, w3};
        const int wy = blk >> 7, bx = blk & 127;
        const void* s = srcs[wy];
        bf16* d = Wc + (size_t)wy * 262144;
        const int i = (bx * 256 + threadIdx.x) * 8;
        bf16x8 v;
        if (flag) {
            const float* f = (const float*)s;
            #pragma unroll
            for (int r = 0; r < 8; ++r) v[r] = (bf16)f[i + r];
        } else {
            v = *(const bf16x8*)((const bf16*)s + i);
        }
        *(bf16x8*)(d + i) = v;
    } else {
        if (threadIdx.x == 0) *flagp = flag;
        const void* srcs[6] = {p0, p1, p2, p3, p4, p5};
        for (int i = threadIdx.x; i < 3072; i += 256) {
            const void* s = srcs[i >> 9];
            const int off = i & 511;
            Pf[i] = flag ? ((const float*)s)[off] : (float)((const bf16*)s)[off];
        }
    }
}

// ---------------------------------------------------------------------------
// GroupNorm v2: q [4][512][4096] -> XN [4][4096][512] bf16.
// 256 blocks = (b, g, pixel-half). Each block streams the FULL group once
// for exact f32 stats (redundant across the half-pair -> no sync), caching
// its own half in LDS ([16][2052] f32, 131 KB, pad kills bank conflicts).
// Pass 2 normalizes from LDS (no second global read) + transposed bf16x8
// writes. Global traffic: 128 MB read + 16 MB write at full-machine BW.
// ---------------------------------------------------------------------------
__global__ __launch_bounds__(256) void groupnorm_k(
    const void* __restrict__ qraw, const float* __restrict__ gamma,
    const float* __restrict__ beta, bf16* __restrict__ XN,
    const int* __restrict__ flag)
{
    __shared__ float Xs[16 * 2052];            // [c][2052] f32, own half
    const int tid = threadIdx.x;
    const int b = blockIdx.x >> 6, g = (blockIdx.x >> 1) & 31, h = blockIdx.x & 1;
    const int f32 = *flag;
    const size_t base = ((size_t)b * 512 + (size_t)g * 16) * 4096;
    const float* sf = (const float*)qraw + base;
    const bf16*  sb = (const bf16*)qraw + base;

    float sum = 0.f, sq = 0.f;
    if (f32) {
        const floatx4* v4 = (const floatx4*)sf;
        for (int idx = tid; idx < 16384; idx += 256) {
            floatx4 v = v4[idx];
            const int c = idx >> 10, px4 = idx & 1023;
            #pragma unroll
            for (int r = 0; r < 4; ++r) { float f = v[r]; sum += f; sq += f * f; }
            if ((px4 >> 9) == h) {
                float* d = &Xs[c * 2052 + px4 * 4 - h * 2048];
                #pragma unroll
                for (int r = 0; r < 4; ++r) d[r] = v[r];
            }
        }
    } else {
        const bf16x8* v8 = (const bf16x8*)sb;
        for (int idx = tid; idx < 8192; idx += 256) {
            bf16x8 v = v8[idx];
            const int c = idx >> 9, px8 = idx & 511;
            float fv[8];
            #pragma unroll
            for (int r = 0; r < 8; ++r) { fv[r] = (float)v[r]; sum += fv[r]; sq += fv[r] * fv[r]; }
            if ((px8 >> 8) == h) {
                float* d = &Xs[c * 2052 + px8 * 8 - h * 2048];
                #pragma unroll
                for (int r = 0; r < 8; ++r) d[r] = fv[r];
            }
        }
    }
    #pragma unroll
    for (int off = 32; off; off >>= 1) {
        sum += __shfl_down(sum, off);
        sq  += __shfl_down(sq, off);
    }
    __shared__ float sS[4], sQ[4];
    __shared__ float s_mean, s_rstd;
    const int wave = tid >> 6, lane = tid & 63;
    if (lane == 0) { sS[wave] = sum; sQ[wave] = sq; }
    __syncthreads();
    if (tid == 0) {
        float ts = sS[0] + sS[1] + sS[2] + sS[3];
        float tq = sQ[0] + sQ[1] + sQ[2] + sQ[3];
        float mean = ts * (1.0f / 65536.0f);
        float var  = tq * (1.0f / 65536.0f) - mean * mean;
        s_mean = mean;
        s_rstd = rsqrtf(fmaxf(var, 0.f) + 1e-6f);
    }
    __syncthreads();
    const float mean = s_mean, rstd = s_rstd;

    float ga[16], be[16];
    #pragma unroll
    for (int c = 0; c < 16; ++c) {
        ga[c] = gamma[g * 16 + c] * rstd;
        be[c] = beta[g * 16 + c] - mean * ga[c];
    }
    bf16* dst = XN + (size_t)b * SBAT + (size_t)g * 16;
    for (int p0 = 0; p0 < 2048; p0 += 256) {
        const int pl = p0 + tid;               // local pixel in [0,2048)
        const int p = h * 2048 + pl;
        bf16x8 o0, o1;
        #pragma unroll
        for (int c = 0; c < 8; ++c)
            o0[c] = (bf16)(Xs[c * 2052 + pl] * ga[c] + be[c]);
        #pragma unroll
        for (int c = 0; c < 8; ++c)
            o1[c] = (bf16)(Xs[(c + 8) * 2052 + pl] * ga[c + 8] + be[c + 8]);
        bf16* dp = dst + (size_t)p * 512;
        *(bf16x8*)dp = o0;
        *(bf16x8*)(dp + 8) = o1;
    }
}

// ---------------------------------------------------------------------------
// Fused attention v3.1 (R7, best measured): producer-consumer waves,
// K-read redundancy halved, P double-buffered.
// Block = (batch, 64 q-rows), 8 waves, 1 blk/CU, 160KB LDS.
//   Waves 0-3 (QK): 2 j-halves x 2 key-halves. Wave = 32 j x 64 keys.
//     Q[32j x 512kd] in regs (128 VGPR); each K frag feeds 2 MFMAs.
//     sub3 tail: exp + packed P(c)-write to buf c&1 + rowsum partial.
//   Waves 4-7 (PV): 128 c-cols each; consume P(c-1) from buf (c-1)&1
//     vs V(c-1) (32x32x16), vb reused x2 across j-halves.
// Per chunk: 4 subs of [vmcnt(0); barrier; stage K+V; role compute].
// LDS: K0@0 K1@32768 [128key][128kd,XOR16]; V0@65536 V1@98304
//      [512c][32i,XOR4]; P0@131072 P1@147456 [64j][128k,XOR16]. 160KB.
// ---------------------------------------------------------------------------
__global__ __launch_bounds__(512, 1) void fused_attn(
    const bf16* __restrict__ QKt,   // [b][4096][1024]: Q cols 0-511, K cols 512-1023
    const bf16* __restrict__ V,     // [b][512][4096]
    bf16* __restrict__ AOt)         // [b][4096][512]
{
    __shared__ __align__(16) char smc[163840];

    const int tid = threadIdx.x;
    const int w = tid >> 6, lane = tid & 63;
    const int fr = lane & 15, quad = lane >> 4;
    const int l5 = lane >> 5, l31 = lane & 31;

    const int ll = blockIdx.x;
    const int xcd = ll & 7, rr = ll >> 3;
    const int b = xcd >> 1;
    const int j0 = ((xcd & 1) * 32 + rr) * 64;

    const bf16* Qb = QKt + (size_t)b * 4194304;
    const bf16* Kb = Qb + 512;
    const bf16* Vb = V + (size_t)b * SBAT;

    const int lcK = ((tid & 15) ^ ((tid >> 4) & 15)) << 3;   // 4-bit involution
    const int rowK = tid >> 4;
    auto stageK = [&](int key0, int kd0, int buf) {
        char* d = smc + buf * 32768;
        const bf16* s0 = Kb + (size_t)(key0 + rowK) * 1024 + kd0 + lcK;
        #pragma unroll
        for (int rho = 0; rho < 4; ++rho)
            __builtin_amdgcn_global_load_lds((GV*)(s0 + (size_t)rho * 32 * 1024),
                (SV*)(d + rho * 8192 + tid * 16), 16, 0, 0);
    };
    const int lcV = ((tid & 3) ^ ((tid >> 3) & 3)) << 3;     // 2-bit involution
    const int rowV = tid >> 2;
    auto stageV = [&](int i0, int buf) {
        char* d = smc + 65536 + buf * 32768;
        const bf16* s0 = Vb + (size_t)rowV * 4096 + i0 + lcV;
        #pragma unroll
        for (int rho = 0; rho < 4; ++rho)
            __builtin_amdgcn_global_load_lds((GV*)(s0 + (size_t)rho * 128 * 4096),
                (SV*)(d + rho * 8192 + tid * 16), 16, 0, 0);
    };
    auto stage_sub = [&](int cc, int s) {
        if (s < 3) {
            if (cc < 32) stageK(cc * 128, (s + 1) * 128, (s + 1) & 1);
            if (cc >= 1 && cc <= 32)
                stageV((cc - 1) * 128 + (s + 1) * 32, (s + 1) & 1);
        } else {
            if (cc < 31) stageK((cc + 1) * 128, 0, 0);
            if (cc < 32) stageV(cc * 128, 0);
        }
    };

    // prologue: K chunk0 slot0 (ALL 512 threads)
    stageK(0, 0, 0);

    if (w < 4) {
        // =================== QK producer path (waves 0-3) ===================
        const int jb = w >> 1;
        const int kw = w & 1;
        bf16x8 qf[2][16];
        #pragma unroll
        for (int jj = 0; jj < 2; ++jj) {
            const bf16* qsrc = Qb +
                (size_t)(j0 + jb * 32 + jj * 16 + fr) * 1024 + quad * 8;
            #pragma unroll
            for (int s = 0; s < 16; ++s)
                qf[jj][s] = *(const bf16x8*)(qsrc + s * 32);
        }
        const int kbase = (kw * 64 + fr) * 256;
        const int pxor = fr << 4;
        const int prow0 = (jb * 32 + fr) * 256;
        const int pcol0 = kw * 128;
        float l_acc0 = 0.f, l_acc1 = 0.f;

        for (int cc = 0; cc <= 32; ++cc) {
            floatx4 acc_s[4][2] = {};
            #pragma unroll
            for (int s = 0; s < 4; ++s) {
                asm volatile("s_waitcnt vmcnt(0)" ::: "memory");
                __builtin_amdgcn_s_barrier();
                stage_sub(cc, s);
                if (cc < 32) {
                    const char* kbuf = smc + (s & 1) * 32768;
                    __builtin_amdgcn_s_setprio(1);
                    #pragma unroll
                    for (int ksl = 0; ksl < 4; ++ksl) {
                        bf16x8 kfr[4];
                        #pragma unroll
                        for (int kf = 0; kf < 4; ++kf)
                            kfr[kf] = *(const bf16x8*)(kbuf + kbase + kf * 4096 +
                                ((((ksl << 2) | quad) ^ fr) << 4));
                        #pragma unroll
                        for (int kf = 0; kf < 4; ++kf) {
                            acc_s[kf][0] = __builtin_amdgcn_mfma_f32_16x16x32_bf16(
                                kfr[kf], qf[0][s * 4 + ksl], acc_s[kf][0], 0, 0, 0);
                            acc_s[kf][1] = __builtin_amdgcn_mfma_f32_16x16x32_bf16(
                                kfr[kf], qf[1][s * 4 + ksl], acc_s[kf][1], 0, 0, 0);
                        }
                    }
                    __builtin_amdgcn_s_setprio(0);
                    if (s == 3) {
                        char* pb = smc + 131072 + (cc & 1) * 16384;
                        float rs0 = 0.f, rs1 = 0.f;
                        #pragma unroll
                        for (int kf = 0; kf < 4; ++kf) {
                            const int cb = (pcol0 + kf * 32 + quad * 8) ^ pxor;
                            bf16x4 pk0, pk1;
                            #pragma unroll
                            for (int r = 0; r < 4; ++r) {
                                float e0 = __expf(fminf(acc_s[kf][0][r] * SCALE_QK, 30.f));
                                float e1 = __expf(fminf(acc_s[kf][1][r] * SCALE_QK, 30.f));
                                rs0 += e0; rs1 += e1;
                                pk0[r] = (bf16)e0; pk1[r] = (bf16)e1;
                            }
                            *(bf16x4*)(pb + prow0 + cb) = pk0;
                            *(bf16x4*)(pb + prow0 + 4096 + cb) = pk1;
                        }
                        rs0 += __shfl_xor(rs0, 16);
                        rs0 += __shfl_xor(rs0, 32);
                        rs1 += __shfl_xor(rs1, 16);
                        rs1 += __shfl_xor(rs1, 32);
                        l_acc0 += rs0; l_acc1 += rs1;
                        asm volatile("s_waitcnt lgkmcnt(0)" ::: "memory");
                    }
                }
            }
        }
        __syncthreads();
        float* lp = (float*)smc;               // [2][64]
        if (lane < 16) {
            lp[kw * 64 + jb * 32 + lane] = l_acc0;
            lp[kw * 64 + jb * 32 + 16 + lane] = l_acc1;
        }
        __syncthreads();
    } else {
        // =================== PV consumer path (waves 4-7) ===================
        const int pw = w - 4;
        const int pxorR = (l31 & 15) << 4;
        floatx16 acc_o[2][4] = {};

        for (int cc = 0; cc <= 32; ++cc) {
            #pragma unroll
            for (int s = 0; s < 4; ++s) {
                asm volatile("s_waitcnt vmcnt(0)" ::: "memory");
                __builtin_amdgcn_s_barrier();
                stage_sub(cc, s);
                if (cc >= 1) {
                    const char* vb = smc + 65536 + (s & 1) * 32768;
                    const char* pb = smc + 131072 + ((cc - 1) & 1) * 16384;
                    __builtin_amdgcn_s_setprio(1);
                    #pragma unroll
                    for (int t = 0; t < 2; ++t) {
                        bf16x8 pa[2];
                        #pragma unroll
                        for (int jf = 0; jf < 2; ++jf)
                            pa[jf] = *(const bf16x8*)(pb + (jf * 32 + l31) * 256 +
                                (((s * 2 + t) * 32 + l5 * 16) ^ pxorR));
                        #pragma unroll
                        for (int nf = 0; nf < 4; ++nf) {
                            const int vc = pw * 128 + nf * 32 + l31;
                            bf16x8 vb8 = *(const bf16x8*)(vb + vc * 64 +
                                ((t * 32 + l5 * 16) ^ (((vc >> 1) & 3) << 4)));
                            acc_o[0][nf] = __builtin_amdgcn_mfma_f32_32x32x16_bf16(
                                pa[0], vb8, acc_o[0][nf], 0, 0, 0);
                            acc_o[1][nf] = __builtin_amdgcn_mfma_f32_32x32x16_bf16(
                                pa[1], vb8, acc_o[1][nf], 0, 0, 0);
                        }
                    }
                    __builtin_amdgcn_s_setprio(0);
                }
            }
        }
        __syncthreads();
        __syncthreads();
        const float* lp = (const float*)smc;

        bf16* out = AOt + (size_t)b * SBAT + (size_t)j0 * 512;
        #pragma unroll
        for (int jf = 0; jf < 2; ++jf) {
            #pragma unroll
            for (int reg = 0; reg < 16; ++reg) {
                const int j = jf * 32 + (reg & 3) + 8 * (reg >> 2) + 4 * l5;
                const float rl = 1.0f / fmaxf(lp[j] + lp[64 + j], 1e-30f);
                #pragma unroll
                for (int nf = 0; nf < 4; ++nf) {
                    const int d = pw * 128 + nf * 32 + l31;
                    out[(size_t)j * 512 + d] = (bf16)(acc_o[jf][nf][reg] * rl);
                }
            }
        }
    }
}

// ---------------------------------------------------------------------------
// 128x128x32 2-phase GEMM (projections + output).
// Epilogues: 0 bias[n] (C=[p][o]) ; 1 bias[m] (C=[o][p]) ; 4 out+residual.
// ---------------------------------------------------------------------------
template <int EPI>
__global__ __launch_bounds__(256, 4) void gemm_xyt(
    const bf16* __restrict__ Xb, const bf16* __restrict__ Yb,
    void* __restrict__ Cv, int N, int K, int lda, int ldb,
    long sX, long sY, long sC,
    const float* __restrict__ bias,
    const void* __restrict__ res, long sR,
    const int* __restrict__ flag)
{
    __shared__ __align__(16) bf16 smem[17408];

    const int tid  = threadIdx.x;
    const int wave = tid >> 6;
    const int lane = tid & 63;
    const int z = blockIdx.z;

    int bx = blockIdx.x, by = blockIdx.y;
    {
        const int gx = gridDim.x, gy = gridDim.y;
        const int o = by * gx + bx;
        const int xcd = o & 7, idx = o >> 3;
        if (gx == 8) {
            bx = xcd;
            by = idx;
        } else if (gx == 32 && gy == 4) {
            bx = (xcd & 1) * 16 + (idx & 15);
            by = xcd >> 1;
        }
    }

    const bf16* X = Xb + (long)z * sX;
    const bf16* Y = Yb + (long)z * sY;
    bf16*  Cb = (bf16*)Cv  + (long)z * sC;
    float* Cf = (float*)Cv + (long)z * sC;
    const int f32o = (EPI == 4) ? *flag : 0;

    const int m0 = by * 128, n0 = bx * 128;
    const int wm = (wave >> 1) * 64, wn = (wave & 1) * 64;
    const int fr = lane & 15, quad = lane >> 4;

    const int srow = tid >> 2;
    const int scol = (tid & 3) * 8;
    const bf16* pX = X + (size_t)(m0 + srow) * lda + scol;
    const bf16* pY = Y + (size_t)(n0 + srow) * ldb + scol;
    const size_t oX = (size_t)64 * lda, oY = (size_t)64 * ldb;
    char* const sb0 = (char*)smem;
    const int ldst = tid * 16;

    auto stage = [&](int k, int pb) {
        char* d = sb0 + pb * 16384;
        const bf16* x = pX + k * 32;
        const bf16* y = pY + k * 32;
        __builtin_amdgcn_global_load_lds((GV*)x,        (SV*)(d + ldst),         16, 0, 0);
        __builtin_amdgcn_global_load_lds((GV*)(x + oX), (SV*)(d + 4096 + ldst),  16, 0, 0);
        __builtin_amdgcn_global_load_lds((GV*)y,        (SV*)(d + 8192 + ldst),  16, 0, 0);
        __builtin_amdgcn_global_load_lds((GV*)(y + oY), (SV*)(d + 12288 + ldst), 16, 0, 0);
    };

    floatx4 acc[4][4] = {};
    const int NK = K >> 5;

    stage(0, 0);
    __syncthreads();

    for (int k = 0; k < NK; ++k) {
        const int p = k & 1;
        if (k + 1 < NK) stage(k + 1, 1 - p);
        const bf16* bA = smem + p * 8192;
        const bf16* bB = bA + 4096;
        bf16x8 af[4], bfr[4];
        #pragma unroll
        for (int i = 0; i < 4; ++i) {
            af[i]  = *(const bf16x8*)&bA[(wm + i * 16 + fr) * 32 + quad * 8];
            bfr[i] = *(const bf16x8*)&bB[(wn + i * 16 + fr) * 32 + quad * 8];
        }
        #pragma unroll
        for (int i = 0; i < 4; ++i)
            #pragma unroll
            for (int j = 0; j < 4; ++j)
                acc[i][j] = __builtin_amdgcn_mfma_f32_16x16x32_bf16(
                    af[i], bfr[j], acc[i][j], 0, 0, 0);
        __syncthreads();
    }

    #pragma unroll
    for (int i = 0; i < 4; ++i) {
        const int mg = m0 + wm + i * 16 + quad * 4;
        float bmr[4];
        if (EPI == 1 || EPI == 4) {
            #pragma unroll
            for (int r = 0; r < 4; ++r) bmr[r] = bias[mg + r];
        }
        #pragma unroll
        for (int j = 0; j < 4; ++j) {
            const int ng = n0 + wn + j * 16 + fr;
            #pragma unroll
            for (int r = 0; r < 4; ++r) {
                float v = acc[i][j][r];
                if (EPI == 0) v += bias[ng];
                if (EPI == 1) v += bmr[r];
                if (EPI == 4) v += bmr[r];
                acc[i][j][r] = v;
            }
        }
    }

    if (EPI != 4) {
        bf16* ct = smem;                       // [128][132] bf16
        #pragma unroll
        for (int i = 0; i < 4; ++i)
            #pragma unroll
            for (int j = 0; j < 4; ++j)
                #pragma unroll
                for (int r = 0; r < 4; ++r)
                    ct[(wm + i * 16 + quad * 4 + r) * 132 + wn + j * 16 + fr] =
                        (bf16)acc[i][j][r];
        __syncthreads();
        #pragma unroll
        for (int w = 0; w < 8; ++w) {
            const int idx = w * 2048 + tid * 8;
            const int row = idx >> 7, col = idx & 127;
            bf16x8 v = *(const bf16x8*)&ct[row * 132 + col];
            *(bf16x8*)&Cb[(size_t)(m0 + row) * N + n0 + col] = v;
        }
    } else if (f32o) {
        float* ct = (float*)smem;              // [64][132] f32, two halves
        const float* rres = (const float*)res + (size_t)z * sR;
        #pragma unroll
        for (int h = 0; h < 2; ++h) {
            if ((wave >> 1) == h) {
                #pragma unroll
                for (int i = 0; i < 4; ++i)
                    #pragma unroll
                    for (int j = 0; j < 4; ++j)
                        #pragma unroll
                        for (int r = 0; r < 4; ++r)
                            ct[(i * 16 + quad * 4 + r) * 132 + wn + j * 16 + fr] =
                                acc[i][j][r];
            }
            __syncthreads();
            #pragma unroll
            for (int w = 0; w < 8; ++w) {
                const int idx = (w * 256 + tid) * 4;
                const int row = idx >> 7, col = idx & 127;
                const size_t o = (size_t)(m0 + h * 64 + row) * N + n0 + col;
                floatx4 v = *(const floatx4*)&ct[row * 132 + col];
                floatx4 rv = *(const floatx4*)&rres[o];
                #pragma unroll
                for (int e = 0; e < 4; ++e) v[e] = (v[e] + rv[e]) * INV_SQRT2F;
                *(floatx4*)&Cf[o] = v;
            }
            __syncthreads();
        }
    } else {
        const bf16* resb = (const bf16*)res + (size_t)z * sR;
        #pragma unroll
        for (int i = 0; i < 4; ++i) {
            const int mg = m0 + wm + i * 16 + quad * 4;
            #pragma unroll
            for (int j = 0; j < 4; ++j) {
                const int ng = n0 + wn + j * 16 + fr;
                #pragma unroll
                for (int r = 0; r < 4; ++r) {
                    const size_t o = (size_t)(mg + r) * N + ng;
                    Cb[o] = (bf16)((acc[i][j][r] + (float)resb[o]) * INV_SQRT2F);
                }
            }
        }
    }
}

// ---------------------------------------------------------------------------
extern "C" void kernel_launch(void* const* d_in, const int* in_sizes, int n_in,
                              void* d_out, int out_size, void* d_ws, size_t ws_size,
                              hipStream_t stream)
{
    const void* q     = d_in[0];
    const void* gamma = d_in[1];
    const void* beta  = d_in[2];
    const void* wq    = d_in[3];
    const void* bq    = d_in[4];
    const void* wk    = d_in[5];
    const void* bk    = d_in[6];
    const void* wv    = d_in[7];
    const void* bv    = d_in[8];
    const void* wo    = d_in[9];
    const void* bo    = d_in[10];

    char* w = (char*)d_ws;
    int*   flag = (int*)w;   w += 16;
    float* Pf   = (float*)w; w += 6 * 512 * 4;      // gamma,beta,bq,bk,bv,bo
    bf16*  Wc   = (bf16*)w;  w += 4 * 262144 * 2;   // wq,wk,wv,wo bf16
    bf16*  XN   = (bf16*)w;  w += TEN * 2;          // reused as AOt
    bf16*  QKt  = (bf16*)w;  w += (size_t)4 * 4096 * 1024 * 2;
    bf16*  V    = (bf16*)w;  w += TEN * 2;
    bf16*  AOt  = XN;

    // merged detect + weight/param conversion (one launch)
    prep_k<<<dim3(513), 256, 0, stream>>>((const unsigned*)q,
        wq, wk, wv, wo, gamma, beta, bq, bk, bv, bo, Wc, Pf, flag);

    groupnorm_k<<<dim3(256), 256, 0, stream>>>(q, Pf, Pf + 512, XN, flag);

    // QKt[p][0:512]=XN.Wq^T+bq, [512:1024]=XN.Wk^T+bk  (merged, N=1024, K=512)
    gemm_xyt<0><<<dim3(8, 32, 4), 256, 0, stream>>>(XN, Wc, QKt,
        1024, 512, 512, 512, SBAT, 0, (long)4096 * 1024, Pf + 1024,
        nullptr, 0, flag);
    // V[o][p] = Wv . XN^T + bv.  N=4096, K=512
    gemm_xyt<1><<<dim3(32, 4, 4), 256, 0, stream>>>(Wc + 2 * 262144, XN, V,
        4096, 512, 512, 512, 0, SBAT, SBAT, Pf + 2048,
        nullptr, 0, flag);

    // Fused scores->exp->PV->(1/l): AOt[b][j][c]  (AOt aliases XN)
    fused_attn<<<dim3(256), 512, 0, stream>>>(QKt, V, AOt);

    // out[o][p] = (Wo . AOt^T + bo + q) * inv_sqrt2.  N=4096, K=512
    gemm_xyt<4><<<dim3(32, 4, 4), 256, 0, stream>>>(Wc + 3 * 262144, AOt, d_out,
        4096, 512, 512, 512, 0, SBAT, SBAT, Pf + 2560,
        q, SBAT, flag);
}